// Round 11
// baseline (684.767 us; speedup 1.0000x reference)
//
#include <hip/hip_runtime.h>

// Problem constants (fixed by reference)
#define N_SRC   100000
#define N_DSTC  50000
#define N_EDGES 1000000
#define DIM     64
#define NCLS    64

// Phased gather: 16 src octiles; waves own 17 contiguous dst rows.
#define NOCT     16
#define OCT_DIV  6250                      // N_SRC / NOCT
#define GATHER_GRID 768                    // 3 blocks/CU (LDS-limited) -> co-resident
#define TOT_WAVES   (GATHER_GRID * 4)      // 3072
#define ROWS_PW     17                     // ceil(N_DSTC / TOT_WAVES)
#define NKEYS    (TOT_WAVES * NOCT)        // 49152 bins (wave, octile)
#define ACC_STRIDE 65                      // LDS row stride (bank spread)

#define SCAN_BPB 1024
#define SCAN_NB  (NKEYS / SCAN_BPB)        // 48

#define HIST_BLOCKS ((N_EDGES / 4 + 255) / 256)        // 977
#define REG_BLOCKS  1024

// ws layout (4-byte slots) -- hist overlays sorted_src (hist dead before
// reorder writes sorted_src):
//   sorted_src [0, 1000000)        int   (hist = [0, 49152) early)
//   colsum     [1000000, +64)      float (zeroed)
//   regA       [1000064]           float (zeroed)
//   regB       [1000065, +64)      float (zeroed)
//   doneG      [1000129]           int   (zeroed)
//   blockSums  [1000130, +48)      int   (fully written by scan_local)
//   cursor     [1000178, +49152)   int   (fully written by scan chain)

__device__ __forceinline__ int edge_key(int d, int s, int* lrow) {
  int w = d / ROWS_PW;                 // owning wave
  *lrow = d - w * ROWS_PW;             // local row 0..16
  return w * NOCT + s / OCT_DIV;       // contiguous 16 keys per wave
}

// ---------------------------------------------------------------------------
// K1: fused key-histogram (blocks [0,HIST_BLOCKS)) and reg A/B accumulation
// (blocks [HIST_BLOCKS, HIST_BLOCKS+REG_BLOCKS)). Disjoint independent work.
__global__ __launch_bounds__(256) void hist_reg_kernel(
    const int4*  __restrict__ src4,
    const int4*  __restrict__ dst4,
    const float* __restrict__ x,
    const float* __restrict__ u_sum,
    int*   __restrict__ hist,
    float* __restrict__ regA,
    float* __restrict__ regB) {
  __shared__ float redB[4][64];
  __shared__ float redA[4];

  if (blockIdx.x < HIST_BLOCKS) {
    int i = blockIdx.x * blockDim.x + threadIdx.x;
    if (i < N_EDGES / 4) {
      int4 s = src4[i];
      int4 d = dst4[i];
      int lr;
      atomicAdd(&hist[edge_key(d.x, s.x, &lr)], 1);
      atomicAdd(&hist[edge_key(d.y, s.y, &lr)], 1);
      atomicAdd(&hist[edge_key(d.z, s.z, &lr)], 1);
      atomicAdd(&hist[edge_key(d.w, s.w, &lr)], 1);
    }
    return;
  }

  // reg part: lane owns column c = lane (pure f32).
  const int tid  = threadIdx.x;
  const int wv   = tid >> 6;
  const int lane = tid & 63;
  const int waveId     = (blockIdx.x - HIST_BLOCKS) * 4 + wv;
  const int totalWaves = REG_BLOCKS * 4;

  float accA = 0.0f;
  float accB = 0.0f;
  for (int r = waveId; r < N_SRC; r += totalWaves) {
    float u  = u_sum[r];                 // wave-uniform -> broadcast
    float xv = x[r * DIM + lane];
    float t  = u * xv;
    accB += t;
    accA = fmaf(t, t, accA);
  }
  #pragma unroll
  for (int off = 32; off > 0; off >>= 1)
    accA += __shfl_down(accA, off, 64);
  if (lane == 0) redA[wv] = accA;
  redB[wv][lane] = accB;
  __syncthreads();
  if (tid < 64) {
    float b = redB[0][tid] + redB[1][tid] + redB[2][tid] + redB[3][tid];
    atomicAdd(&regB[tid], b);
  }
  if (tid == 0) {
    float a = redA[0] + redA[1] + redA[2] + redA[3];
    atomicAdd(regA, a);
  }
}

// ---------------------------------------------------------------------------
// K2a: per-block (1024 keys) exclusive scan; emit block totals.
__global__ __launch_bounds__(1024) void scan_local(
    const int* __restrict__ hist, int* __restrict__ cursor,
    int* __restrict__ blockSums) {
  __shared__ int A[1024], B[1024];
  const int b = blockIdx.x, t = threadIdx.x;
  const int g = b * SCAN_BPB + t;
  int v = hist[g];
  A[t] = v;
  __syncthreads();
  int* cur = A; int* nxt = B;
  for (int off = 1; off < 1024; off <<= 1) {
    int s = cur[t] + ((t >= off) ? cur[t - off] : 0);
    nxt[t] = s;
    __syncthreads();
    int* tmp = cur; cur = nxt; nxt = tmp;
  }
  cursor[g] = cur[t] - v;   // exclusive within block
  if (t == 1023) blockSums[b] = cur[1023];
}

// K2b: each block redundantly scans the 48 block totals in LDS, then adds
// its own block offset to its 1024 cursor entries.
__global__ __launch_bounds__(1024) void scan_addoff(
    int* __restrict__ cursor, const int* __restrict__ blockSums) {
  __shared__ int A[1024], B[1024];
  const int b = blockIdx.x, t = threadIdx.x;
  A[t] = (t < SCAN_NB) ? blockSums[t] : 0;
  __syncthreads();
  int* cur = A; int* nxt = B;
  for (int off = 1; off < 64; off <<= 1) {
    int s = cur[t] + ((t >= off) ? cur[t - off] : 0);
    nxt[t] = s;
    __syncthreads();
    int* tmp = cur; cur = nxt; nxt = tmp;
  }
  int off = (b > 0) ? cur[b - 1] : 0;   // exclusive offset of block b
  cursor[b * SCAN_BPB + t] += off;
}

// ---------------------------------------------------------------------------
// K3: counting-sort pass 2 on key=(wave, octile); value packs src|(lrow<<17).
// After this kernel cursor[k] == end offset of key k.
__global__ __launch_bounds__(256) void reorder_kernel(
    const int4* __restrict__ src4, const int4* __restrict__ dst4,
    int* __restrict__ cursor, int* __restrict__ sorted_src) {
  int i = blockIdx.x * blockDim.x + threadIdx.x;
  if (i < N_EDGES / 4) {
    int4 s = src4[i];
    int4 d = dst4[i];
    int l0, l1, l2, l3;
    int k0 = edge_key(d.x, s.x, &l0);
    int k1 = edge_key(d.y, s.y, &l1);
    int k2 = edge_key(d.z, s.z, &l2);
    int k3 = edge_key(d.w, s.w, &l3);
    int p0 = atomicAdd(&cursor[k0], 1); sorted_src[p0] = s.x | (l0 << 17);
    int p1 = atomicAdd(&cursor[k1], 1); sorted_src[p1] = s.y | (l1 << 17);
    int p2 = atomicAdd(&cursor[k2], 1); sorted_src[p2] = s.z | (l2 << 17);
    int p3 = atomicAdd(&cursor[k3], 1); sorted_src[p3] = s.w | (l3 << 17);
  }
}

// ---------------------------------------------------------------------------
// K4: persistent phased gather with per-wave LDS accumulators.
// Wave owns rows [waveId*17, +17). Phase oc: one contiguous segment
// [cursor[key-1], cursor[key]) with key = waveId*16+oc (~21 edges avg).
// Per quad: 1 shfl broadcasts packed (src,lrow); subgroup es gathers its
// edge's 256B row as 16xfloat4 and ds_add_f32's into acc[lrow].
__global__ __launch_bounds__(256, 3) void gather_h(
    const float* __restrict__ x,
    const float* __restrict__ Ww,   // [64][128]
    const float* __restrict__ Wb,   // [64]
    const int*   __restrict__ cursor,      // end offsets after reorder
    const int*   __restrict__ sorted_src,  // packed src|(lrow<<17)
    float* __restrict__ h,
    float* __restrict__ colsum,
    float* __restrict__ regA,
    float* __restrict__ regB,
    int*   __restrict__ doneG,
    float* __restrict__ out_scalar) {
  __shared__ float Wt[2 * DIM][NCLS + 1];          // 33,280 B
  __shared__ float accS[4 * ROWS_PW * ACC_STRIDE]; // 17,680 B
  __shared__ int   cntS[4 * ROWS_PW];
  __shared__ float colred[4][64];
  __shared__ int   lastFlag;

  const int tid  = threadIdx.x;
  const int wv   = tid >> 6;
  const int lane = tid & 63;
  const int es   = lane >> 4;
  const int q    = lane & 15;

  // init per-wave acc + counts, stage Wt
  for (int i = lane; i < ROWS_PW * ACC_STRIDE; i += 64)
    accS[wv * ROWS_PW * ACC_STRIDE + i] = 0.0f;
  if (lane < ROWS_PW) cntS[wv * ROWS_PW + lane] = 0;
  for (int idx = tid; idx < NCLS * 2 * DIM; idx += 256) {
    int c = idx >> 7, k = idx & 127;
    Wt[k][c] = Ww[idx];
  }
  __syncthreads();

  const int waveId = blockIdx.x * 4 + wv;      // 0..3071
  const float bias = Wb[lane];
  const float4* x4 = reinterpret_cast<const float4*>(x);
  float* myAcc = accS + wv * ROWS_PW * ACC_STRIDE;
  int*   myCnt = cntS + wv * ROWS_PW;

  // ---- phased gather: one src octile at a time ----
  for (int oc = 0; oc < NOCT; ++oc) {
    int key = waveId * NOCT + oc;
    int beg = (key == 0) ? 0 : cursor[key - 1];
    int end = cursor[key];
    for (int base = beg; base < end; base += 64) {
      int rem = end - base;
      int mm  = rem < 64 ? rem : 64;
      int pv  = (lane < rem) ? sorted_src[base + lane] : 0;
      for (int jb = 0; jb < mm; jb += 4) {
        int j = jb + es;
        int p = __shfl(pv, j & 63, 64);
        if (j < mm) {
          int s0 = p & 0x1FFFF;
          int lr = p >> 17;
          float4 v = x4[s0 * 16 + q];
          float* ap = myAcc + lr * ACC_STRIDE + q * 4;
          atomicAdd(ap + 0, v.x);
          atomicAdd(ap + 1, v.y);
          atomicAdd(ap + 2, v.z);
          atomicAdd(ap + 3, v.w);
          if (q == 0) atomicAdd(&myCnt[lr], 1);
        }
      }
    }
    __syncthreads();   // phase alignment within block (not for correctness)
  }

  // ---- epilogue: mean, GEMV, colsum (lane == column) ----
  float colacc = 0.0f;
  #pragma unroll
  for (int j = 0; j < ROWS_PW; ++j) {
    int r = waveId * ROWS_PW + j;
    if (r < N_DSTC) {
      float ysum = myAcc[j * ACC_STRIDE + lane];
      int   cnt  = myCnt[j];
      float ym   = ysum / fmaxf((float)cnt, 1.0f);
      colacc += ym;
      float xv = x[r * DIM + lane];
      float hacc = bias;
      #pragma unroll
      for (int k = 0; k < DIM; ++k) {
        float fx = __shfl(xv, k, 64);
        float fy = __shfl(ym, k, 64);
        hacc = fmaf(fx, Wt[k][lane], hacc);
        hacc = fmaf(fy, Wt[DIM + k][lane], hacc);
      }
      h[r * NCLS + lane] = hacc;
    }
  }

  colred[wv][lane] = colacc;
  __syncthreads();
  if (tid < 64) {
    float s = colred[0][tid] + colred[1][tid] + colred[2][tid] + colred[3][tid];
    atomicAdd(&colsum[tid], s);
  }

  // ---- last-block reg-loss combine ----
  __syncthreads();
  if (tid == 0) {
    __threadfence();
    int old = atomicAdd(doneG, 1);
    lastFlag = (old == (int)gridDim.x - 1) ? 1 : 0;
  }
  __syncthreads();
  if (lastFlag && tid < 64) {
    const float inv_nd = 1.0f / (float)N_DSTC;
    float cs = atomicAdd(&colsum[tid], 0.0f);   // coherent atomic read
    float bv = atomicAdd(&regB[tid], 0.0f);
    float mx = cs * inv_nd;
    float p = fmaf((float)N_SRC * mx, mx, -2.0f * inv_nd * mx * bv);
    #pragma unroll
    for (int off = 32; off > 0; off >>= 1)
      p += __shfl_down(p, off, 64);
    if (tid == 0) {
      float av = atomicAdd(regA, 0.0f);
      float total = fmaf(av, inv_nd * inv_nd, p);
      out_scalar[0] = total * (1.0f / ((float)N_SRC * (float)NCLS));
    }
  }
}

// ---------------------------------------------------------------------------
extern "C" void kernel_launch(void* const* d_in, const int* in_sizes, int n_in,
                              void* d_out, int out_size, void* d_ws, size_t ws_size,
                              hipStream_t stream) {
  const float* x     = (const float*)d_in[0];
  // d_in[1] = w : dead (only ones_like(w) is used)
  const float* u_sum = (const float*)d_in[2];
  const float* Ww    = (const float*)d_in[3];
  const float* Wb    = (const float*)d_in[4];
  const int*   src   = (const int*)d_in[5];
  const int*   dst   = (const int*)d_in[6];

  float* out = (float*)d_out;
  int*   wsI = (int*)d_ws;

  int*   sorted_src = wsI;                        // [0, 1,000,000)
  int*   hist       = wsI;                        // overlays sorted_src front
  float* colsum     = (float*)(wsI + 1000000);    // 64
  float* regA       = colsum + 64;                // 1
  float* regB       = regA + 1;                   // 64
  int*   doneG      = (int*)(regB + 64);          // 1
  int*   blockSums  = doneG + 1;                  // 48
  int*   cursor     = blockSums + SCAN_NB;        // 49,152

  // zero: hist (49152) and colsum/regA/regB/doneG (130)
  hipMemsetAsync(hist, 0, (size_t)NKEYS * sizeof(int), stream);
  hipMemsetAsync(colsum, 0, (size_t)(64 + 1 + 64 + 1) * sizeof(int), stream);

  hist_reg_kernel<<<HIST_BLOCKS + REG_BLOCKS, 256, 0, stream>>>(
      (const int4*)src, (const int4*)dst, x, u_sum, hist, regA, regB);
  scan_local  <<<SCAN_NB, 1024, 0, stream>>>(hist, cursor, blockSums);
  scan_addoff <<<SCAN_NB, 1024, 0, stream>>>(cursor, blockSums);
  reorder_kernel<<<(N_EDGES / 4 + 255) / 256, 256, 0, stream>>>(
      (const int4*)src, (const int4*)dst, cursor, sorted_src);
  gather_h    <<<GATHER_GRID, 256, 0, stream>>>(
      x, Ww, Wb, cursor, sorted_src, out, colsum, regA, regB, doneG,
      out + (size_t)N_DSTC * NCLS);
}

// Round 12
// 462.995 us; speedup vs baseline: 1.4790x; 1.4790x over previous
//
#include <hip/hip_runtime.h>

// Problem constants (fixed by reference)
#define N_SRC   100000
#define N_DSTC  50000
#define N_EDGES 1000000
#define DIM     64
#define NCLS    64

#define HIST_BLOCKS ((N_EDGES / 4 + 255) / 256)        // 977
#define REG_BLOCKS  1024
#define GATHER_GRID 2048

// ws layout (4-byte slots), zero region = [0, 50130):
//   hist    [0, 50000)        int
//   colsum  [50000, 50064)    float
//   regA    [50064]           float   Sum (u*x)^2
//   regB    [50065, 50129)    float   Sum_r u_r * x[r][c]
//   doneG   [50129]           int
//   cursor  [50130, 100130)   int   (fully written by scan)
//   sorted_src [100130, 1100130) int (fully written by reorder)

// ---------------------------------------------------------------------------
// K1: fused histogram (blocks [0,HIST_BLOCKS)) + reg A/B accumulation
// (blocks [HIST_BLOCKS, HIST_BLOCKS+REG_BLOCKS)). Disjoint independent work.
__global__ __launch_bounds__(256) void hist_reg_kernel(
    const int4*  __restrict__ dst4,
    const float* __restrict__ x,
    const float* __restrict__ u_sum,
    int*   __restrict__ hist,
    float* __restrict__ regA,
    float* __restrict__ regB) {
  __shared__ float redB[4][64];
  __shared__ float redA[4];

  if (blockIdx.x < HIST_BLOCKS) {
    int i = blockIdx.x * blockDim.x + threadIdx.x;
    if (i < N_EDGES / 4) {
      int4 d = dst4[i];
      atomicAdd(&hist[d.x], 1);
      atomicAdd(&hist[d.y], 1);
      atomicAdd(&hist[d.z], 1);
      atomicAdd(&hist[d.w], 1);
    }
    return;
  }

  // reg part: lane owns column c = lane (pure f32).
  const int tid  = threadIdx.x;
  const int wv   = tid >> 6;
  const int lane = tid & 63;
  const int waveId     = (blockIdx.x - HIST_BLOCKS) * 4 + wv;
  const int totalWaves = REG_BLOCKS * 4;

  float accA = 0.0f;
  float accB = 0.0f;
  for (int r = waveId; r < N_SRC; r += totalWaves) {
    float u  = u_sum[r];                 // wave-uniform -> broadcast
    float xv = x[r * DIM + lane];
    float t  = u * xv;
    accB += t;
    accA = fmaf(t, t, accA);
  }
  #pragma unroll
  for (int off = 32; off > 0; off >>= 1)
    accA += __shfl_down(accA, off, 64);
  if (lane == 0) redA[wv] = accA;
  redB[wv][lane] = accB;
  __syncthreads();
  if (tid < 64) {
    float b = redB[0][tid] + redB[1][tid] + redB[2][tid] + redB[3][tid];
    atomicAdd(&regB[tid], b);
  }
  if (tid == 0) {
    float a = redA[0] + redA[1] + redA[2] + redA[3];
    atomicAdd(regA, a);
  }
}

// ---------------------------------------------------------------------------
// K2: single-block exclusive scan -> cursor (start offsets). Ping-pong
// double-buffered (R4-bench-proven code).
__global__ __launch_bounds__(1024) void scan_kernel(
    const int* __restrict__ hist, int* __restrict__ cursor) {
  __shared__ int bufA[1024];
  __shared__ int bufB[1024];
  const int t = threadIdx.x;
  const int chunk = (N_DSTC + 1023) / 1024;  // 49
  int beg = t * chunk;       if (beg > N_DSTC) beg = N_DSTC;
  int end = beg + chunk;     if (end > N_DSTC) end = N_DSTC;

  int s = 0;
  for (int i = beg; i < end; ++i) s += hist[i];
  bufA[t] = s;
  __syncthreads();

  int* cur = bufA;
  int* nxt = bufB;
  for (int off = 1; off < 1024; off <<= 1) {
    int v = cur[t] + ((t >= off) ? cur[t - off] : 0);
    nxt[t] = v;
    __syncthreads();
    int* tmp = cur; cur = nxt; nxt = tmp;
  }
  int run = (t > 0) ? cur[t - 1] : 0;
  for (int i = beg; i < end; ++i) {
    cursor[i] = run;
    run += hist[i];
  }
}

// ---------------------------------------------------------------------------
// K3: counting-sort pass 2, 1 edge/thread (max scatter parallelism).
// After this kernel cursor[i] == end offset of bin i.
__global__ __launch_bounds__(256) void reorder_kernel(
    const int* __restrict__ src, const int* __restrict__ dst,
    int* __restrict__ cursor, int* __restrict__ sorted_src) {
  int e = blockIdx.x * blockDim.x + threadIdx.x;
  if (e < N_EDGES) {
    int pos = atomicAdd(&cursor[dst[e]], 1);
    sorted_src[pos] = src[e];
  }
}

// ---------------------------------------------------------------------------
// K4: fused gather + mean + GEMV + colsum + last-block reg combine.
// R4-VERBATIM gather machinery: one dst row per wave; es = lane>>4 edge
// subgroup, q = lane&15 float4 quadrant; 1-deep predicated inner loop;
// grid 2048; plain __launch_bounds__(256) (VGPR ~112, ~21% occ -- the
// empirically optimal config, see R4/R5/R6/R8 ledger).
__global__ __launch_bounds__(256) void gather_h(
    const float* __restrict__ x,
    const float* __restrict__ Ww,   // [64][128]
    const float* __restrict__ Wb,   // [64]
    const int*   __restrict__ cursor,      // end offsets after reorder
    const int*   __restrict__ sorted_src,
    float* __restrict__ h,
    float* __restrict__ colsum,
    float* __restrict__ regA,
    float* __restrict__ regB,
    int*   __restrict__ doneG,
    float* __restrict__ out_scalar) {
  __shared__ float Wt[2 * DIM][NCLS + 1];  // Wt[k][c] = Ww[c*128+k]
  __shared__ float colred[4][64];
  __shared__ int   lastFlag;

  const int tid = threadIdx.x;
  for (int idx = tid; idx < NCLS * 2 * DIM; idx += 256) {
    int c = idx >> 7, k = idx & 127;
    Wt[k][c] = Ww[idx];
  }
  __syncthreads();

  const int wv   = tid >> 6;
  const int lane = tid & 63;
  const int es   = lane >> 4;
  const int q    = lane & 15;
  const int waveId = blockIdx.x * 4 + wv;
  const int tw     = gridDim.x * 4;
  const float bias = Wb[lane];
  const float4* x4 = reinterpret_cast<const float4*>(x);

  float4 colacc = make_float4(0.f, 0.f, 0.f, 0.f);

  for (int r = waveId; r < N_DSTC; r += tw) {
    int beg = (r == 0) ? 0 : cursor[r - 1];
    int end = cursor[r];
    int cnt = end - beg;

    float4 a = make_float4(0.f, 0.f, 0.f, 0.f);
    for (int base = 0; base < cnt; base += 64) {
      int rem = cnt - base;
      int mm  = rem < 64 ? rem : 64;
      int idxv = (lane < rem) ? sorted_src[beg + base + lane] : 0;
      int nIt = (mm + 3) >> 2;
      for (int jj = 0; jj < nIt; ++jj) {
        int j = (jj << 2) + es;            // this subgroup's edge slot
        int sIdx = __shfl(idxv, j & 63, 64);  // uniform execution
        if (j < mm) {
          float4 v = x4[(long long)sIdx * 16 + q];
          a.x += v.x; a.y += v.y; a.z += v.z; a.w += v.w;
        }
      }
    }
    // reduce across the 4 edge subgroups
    a.x += __shfl_xor(a.x, 16, 64); a.y += __shfl_xor(a.y, 16, 64);
    a.z += __shfl_xor(a.z, 16, 64); a.w += __shfl_xor(a.w, 16, 64);
    a.x += __shfl_xor(a.x, 32, 64); a.y += __shfl_xor(a.y, 32, 64);
    a.z += __shfl_xor(a.z, 32, 64); a.w += __shfl_xor(a.w, 32, 64);

    float inv = 1.0f / fmaxf((float)cnt, 1.0f);
    float4 ym = make_float4(a.x * inv, a.y * inv, a.z * inv, a.w * inv);

    float4 xv = x4[(long long)r * 16 + q];   // same 256B row for whole wave

    if (es == 0) {
      colacc.x += ym.x; colacc.y += ym.y; colacc.z += ym.z; colacc.w += ym.w;
    }

    float hacc = bias;
    #pragma unroll
    for (int k = 0; k < DIM; ++k) {
      const int sl = k >> 2;  // es==0 lane holding quadrant k>>2
      float fx = __shfl((k & 3) == 0 ? xv.x : (k & 3) == 1 ? xv.y :
                        (k & 3) == 2 ? xv.z : xv.w, sl, 64);
      float fy = __shfl((k & 3) == 0 ? ym.x : (k & 3) == 1 ? ym.y :
                        (k & 3) == 2 ? ym.z : ym.w, sl, 64);
      hacc = fmaf(fx, Wt[k][lane], hacc);
      hacc = fmaf(fy, Wt[DIM + k][lane], hacc);
    }
    h[(long long)r * NCLS + lane] = hacc;
  }

  if (es == 0) {  // lane q owns columns 4q..4q+3
    colred[wv][q * 4 + 0] = colacc.x;
    colred[wv][q * 4 + 1] = colacc.y;
    colred[wv][q * 4 + 2] = colacc.z;
    colred[wv][q * 4 + 3] = colacc.w;
  }
  __syncthreads();
  if (tid < 64) {
    float s = colred[0][tid] + colred[1][tid] + colred[2][tid] + colred[3][tid];
    atomicAdd(&colsum[tid], s);
  }

  // ---- last-block reg-loss combine ----
  __syncthreads();
  if (tid == 0) {
    __threadfence();
    int old = atomicAdd(doneG, 1);
    lastFlag = (old == (int)gridDim.x - 1) ? 1 : 0;
  }
  __syncthreads();
  if (lastFlag && tid < 64) {
    const float inv_nd = 1.0f / (float)N_DSTC;
    float cs = atomicAdd(&colsum[tid], 0.0f);   // coherent atomic read
    float bv = atomicAdd(&regB[tid], 0.0f);
    float mx = cs * inv_nd;
    float p = fmaf((float)N_SRC * mx, mx, -2.0f * inv_nd * mx * bv);
    #pragma unroll
    for (int off = 32; off > 0; off >>= 1)
      p += __shfl_down(p, off, 64);
    if (tid == 0) {
      float av = atomicAdd(regA, 0.0f);
      float total = fmaf(av, inv_nd * inv_nd, p);
      out_scalar[0] = total * (1.0f / ((float)N_SRC * (float)NCLS));
    }
  }
}

// ---------------------------------------------------------------------------
extern "C" void kernel_launch(void* const* d_in, const int* in_sizes, int n_in,
                              void* d_out, int out_size, void* d_ws, size_t ws_size,
                              hipStream_t stream) {
  const float* x     = (const float*)d_in[0];
  // d_in[1] = w : dead (only ones_like(w) is used)
  const float* u_sum = (const float*)d_in[2];
  const float* Ww    = (const float*)d_in[3];
  const float* Wb    = (const float*)d_in[4];
  const int*   src   = (const int*)d_in[5];
  const int*   dst   = (const int*)d_in[6];

  float* out = (float*)d_out;
  int*   wsI = (int*)d_ws;

  int*   hist       = wsI;                        // 50000
  float* colsum     = (float*)(wsI + N_DSTC);     // 64
  float* regA       = colsum + 64;                // 1
  float* regB       = regA + 1;                   // 64
  int*   doneG      = (int*)(regB + 64);          // 1
  int*   cursor     = doneG + 1;                  // 50000
  int*   sorted_src = cursor + N_DSTC;            // 1,000,000

  // zero: hist + colsum + regA + regB + doneG (contiguous front region)
  hipMemsetAsync(d_ws, 0, (size_t)(N_DSTC + 64 + 1 + 64 + 1) * sizeof(int), stream);

  hist_reg_kernel<<<HIST_BLOCKS + REG_BLOCKS, 256, 0, stream>>>(
      (const int4*)dst, x, u_sum, hist, regA, regB);
  scan_kernel   <<<1, 1024, 0, stream>>>(hist, cursor);
  reorder_kernel<<<(N_EDGES + 255) / 256, 256, 0, stream>>>(
      src, dst, cursor, sorted_src);
  gather_h      <<<GATHER_GRID, 256, 0, stream>>>(
      x, Ww, Wb, cursor, sorted_src, out, colsum, regA, regB, doneG,
      out + (size_t)N_DSTC * NCLS);
}